// Round 1
// baseline (314.745 us; speedup 1.0000x reference)
//
#include <hip/hip_runtime.h>
#include <math.h>

#define NB 5      // boxes per cell
#define NC 80     // classes
#define DD 85     // 5 + NC
#define CH 425    // NB * DD
#define EPSF 1e-6f

__global__ __launch_bounds__(256) void yolo_loss_kernel(
    const float* __restrict__ preds,
    const float* __restrict__ targets,
    float* __restrict__ out,
    int ncells)
{
    const int tid   = threadIdx.x;
    const int lane  = tid & 15;          // lane within 16-lane group
    const int grp   = tid >> 4;          // group within block (0..15)
    const long long g0      = (long long)blockIdx.x * 16 + grp;
    const long long gstride = (long long)gridDim.x * 16;

    float acc = 0.0f;

    for (long long cell = g0; cell < ncells; cell += gstride) {
        const long long base = cell * CH;
        const float* pc = preds + base;
        const float* tc = targets + base;

        // ---- load the 5 target and 5 pred box records (lanes 0..4) ----
        float tx=0.f, ty=0.f, tw=0.f, th=0.f, tconf=0.f;
        float px=0.f, py=0.f, pw=0.f, ph=0.f, pconf=0.f;
        if (lane < NB) {
            const float* tb = tc + lane * DD;
            tx = tb[0]; ty = tb[1]; tw = tb[2]; th = tb[3]; tconf = tb[4];
            const float* pb = pc + lane * DD;
            px = pb[0]; py = pb[1]; pw = pb[2]; ph = pb[3]; pconf = pb[4];
        }
        // target corners (reference-style) per lane
        const float tx1 = tx - tw * 0.5f;
        const float ty1 = ty - th * 0.5f;
        const float tx2 = tx + tw * 0.5f;
        const float ty2 = ty + th * 0.5f;
        const float area_t = (tx2 - tx1) * (ty2 - ty1);

        #pragma unroll
        for (int b = 0; b < NB; ++b) {
            // broadcast pred box b to all 16 lanes
            const float bx    = __shfl(px,    b, 16);
            const float by    = __shfl(py,    b, 16);
            const float bw    = __shfl(pw,    b, 16);
            const float bh    = __shfl(ph,    b, 16);
            const float bconf = __shfl(pconf, b, 16);

            // IoU of pred box b vs this lane's target box (lanes 0..4)
            const float px1 = bx - bw * 0.5f;
            const float py1 = by - bh * 0.5f;
            const float px2 = bx + bw * 0.5f;
            const float py2 = by + bh * 0.5f;
            float iw = fminf(px2, tx2) - fmaxf(px1, tx1); iw = fmaxf(iw, 0.0f);
            float ih = fminf(py2, ty2) - fmaxf(py1, ty1); ih = fmaxf(ih, 0.0f);
            const float inter  = iw * ih;
            const float area_p = (px2 - px1) * (py2 - py1);
            const float iou    = inter / (area_p + area_t - inter + EPSF);

            // argmax over the 5 targets, first-index tie-break (butterfly, width 16)
            float v  = (lane < NB) ? iou : -INFINITY;
            int   vi = (lane < NB) ? lane : 0x7fffffff;
            #pragma unroll
            for (int m = 1; m < 16; m <<= 1) {
                const float ov = __shfl_xor(v, m, 16);
                const int   oi = __shfl_xor(vi, m, 16);
                if (ov > v || (ov == v && oi < vi)) { v = ov; vi = oi; }
            }
            const int best = vi;

            // matched target record
            const float mx    = __shfl(tx,    best, 16);
            const float my    = __shfl(ty,    best, 16);
            const float mw    = __shfl(tw,    best, 16);
            const float mh    = __shfl(th,    best, 16);
            const float mconf = __shfl(tconf, best, 16);

            // ---- class part: 80 logits, 5 per lane ----
            const float* pcl = pc + b * DD + 5;
            const float* tcl = tc + b * DD + 5;
            float pl[5], tl[5];
            #pragma unroll
            for (int k = 0; k < 5; ++k) {
                pl[k] = pcl[lane + 16 * k];
                tl[k] = tcl[lane + 16 * k];
            }
            // log-softmax denom of pred logits
            float mx5 = pl[0];
            #pragma unroll
            for (int k = 1; k < 5; ++k) mx5 = fmaxf(mx5, pl[k]);
            #pragma unroll
            for (int m = 1; m < 16; m <<= 1) mx5 = fmaxf(mx5, __shfl_xor(mx5, m, 16));
            float se = 0.0f;
            #pragma unroll
            for (int k = 0; k < 5; ++k) se += __expf(pl[k] - mx5);
            #pragma unroll
            for (int m = 1; m < 16; m <<= 1) se += __shfl_xor(se, m, 16);
            const float logZ = mx5 + __logf(se);

            // argmax of target logits (first-index tie-break), carrying pred logit
            float bv = tl[0]; int bi = lane; float bp = pl[0];
            #pragma unroll
            for (int k = 1; k < 5; ++k) {
                const int ci = lane + 16 * k;
                if (tl[k] > bv) { bv = tl[k]; bi = ci; bp = pl[k]; }
            }
            #pragma unroll
            for (int m = 1; m < 16; m <<= 1) {
                const float ov = __shfl_xor(bv, m, 16);
                const int   oi = __shfl_xor(bi, m, 16);
                const float op = __shfl_xor(bp, m, 16);
                if (ov > bv || (ov == bv && oi < bi)) { bv = ov; bi = oi; bp = op; }
            }
            // nll = logZ - p_logit[tcls]
            const float nll = logZ - bp;

            // ---- accumulate loss terms on lane b only ----
            if (lane == b) {
                const float obj = (mconf > 0.0f) ? 1.0f : 0.0f;
                float term;
                const float dx = bx - mx, dy = by - my;
                term = 5.0f * obj * (dx * dx + dy * dy);
                const float spw = sqrtf(fabsf(bw + EPSF));
                const float sph = sqrtf(fabsf(bh + EPSF));
                const float smw = sqrtf(fabsf(mw + EPSF));
                const float smh = sqrtf(fabsf(mh + EPSF));
                const float dw = spw - smw, dh = sph - smh;
                term += 5.0f * obj * (dw * dw + dh * dh);
                const float dc = bconf - mconf;
                const float csq = dc * dc;
                term += obj * csq + 0.5f * (1.0f - obj) * csq;
                term += obj * nll;
                acc += term;
            }
        }
    }

    // ---- block reduction ----
    #pragma unroll
    for (int off = 32; off > 0; off >>= 1) acc += __shfl_down(acc, off, 64);
    __shared__ float wsum[4];
    if ((tid & 63) == 0) wsum[tid >> 6] = acc;
    __syncthreads();
    if (tid == 0) {
        const float s = wsum[0] + wsum[1] + wsum[2] + wsum[3];
        atomicAdd(out, s);
    }
}

extern "C" void kernel_launch(void* const* d_in, const int* in_sizes, int n_in,
                              void* d_out, int out_size, void* d_ws, size_t ws_size,
                              hipStream_t stream) {
    const float* preds   = (const float*)d_in[0];
    const float* targets = (const float*)d_in[1];
    float* out = (float*)d_out;

    const int ncells = in_sizes[0] / CH;   // 128*26*26 = 86528
    const int blocks = (ncells + 15) / 16; // one 16-lane group per cell

    hipMemsetAsync(out, 0, sizeof(float), stream);
    yolo_loss_kernel<<<blocks, 256, 0, stream>>>(preds, targets, out, ncells);
}